// Round 2
// baseline (646.635 us; speedup 1.0000x reference)
//
#include <hip/hip_runtime.h>
#include <hip/hip_cooperative_groups.h>
#include <math.h>

namespace cg = cooperative_groups;

#define DIM 128
#define NATOMS 8192
#define LPROT 8192
#define CAP 64
#define NF (NATOMS*DIM)

// ---------------- prep: both gathers + 4 weight transposes ----------------
__global__ __launch_bounds__(256) void k_prep(
    const int* __restrict__ fp, const int* __restrict__ words,
    const float* __restrict__ emb_fp, const float* __restrict__ emb_w,
    const float* __restrict__ Wg, const float* __restrict__ Wa,
    float* __restrict__ xs, float* __restrict__ xsp,
    float* __restrict__ WgT, float* __restrict__ WaT) {
  int b = blockIdx.x, tid = threadIdx.x;
  if (b < 1024) {                      // gather atoms
    int i = b * 256 + tid;
    int row = i >> 5, c4 = i & 31;
    const float4* s = (const float4*)(emb_fp + (size_t)fp[row] * DIM);
    ((float4*)(xs + (size_t)row * DIM))[c4] = s[c4];
  } else if (b < 2048) {               // gather words
    int i = (b - 1024) * 256 + tid;
    int row = i >> 5, c4 = i & 31;
    const float4* s = (const float4*)(emb_w + (size_t)words[row] * DIM);
    ((float4*)(xsp + (size_t)row * DIM))[c4] = s[c4];
  } else {                             // transpose Wg[0..2], Wa (32x32 tiles)
    __shared__ float tile[32][33];
    int sub = b - 2048;
    int m = sub >> 4, t = sub & 15;
    int tx = t & 3, ty = t >> 2;
    const float* src = (m < 3) ? Wg + m * DIM * DIM : Wa;
    float*       dst = (m < 3) ? WgT + m * DIM * DIM : WaT;
    int x = tid & 31, y0 = tid >> 5;
    int xg = tx * 32 + x;
    for (int i = y0; i < 32; i += 8)
      tile[i][x] = src[(ty * 32 + i) * DIM + xg];
    __syncthreads();
    int xo = ty * 32 + x;
    for (int i = y0; i < 32; i += 8)
      dst[(tx * 32 + i) * DIM + xo] = tile[x][i];
  }
}

// ---------------- build ELL from dense binary adjacency ----------------
__global__ void k_build_ell(const float* __restrict__ adj, int* __restrict__ ell,
                            int* __restrict__ cnt) {
  int wv = threadIdx.x >> 6, lane = threadIdx.x & 63;
  int row = blockIdx.x * 4 + wv;
  const float4* rp = (const float4*)(adj + (size_t)row * NATOMS);
  int* er = ell + (size_t)row * CAP;
  int c = 0;
  for (int it = 0; it < NATOMS / 256; ++it) {
    float4 v = rp[(size_t)it * 64 + lane];
    float f[4] = {v.x, v.y, v.z, v.w};
    #pragma unroll
    for (int j = 0; j < 4; ++j) {
      bool nz = (f[j] != 0.0f);
      unsigned long long m = __ballot(nz);
      if (nz) {
        int pos = c + __popcll(m & ((1ull << lane) - 1ull));
        if (pos < CAP) er[pos] = it * 256 + lane * 4 + j;
      }
      c += __popcll(m);
    }
  }
  if (lane == 0) cnt[row] = c > CAP ? CAP : c;
}

// ---------------- cooperative GNN: 3x (gemm_relu -> spmv) + colsum + xchain ----------------
__global__ __launch_bounds__(256) void k_gnn(
    const float* __restrict__ WgT, const float* __restrict__ bg,
    const float* __restrict__ WaT, const float* __restrict__ ba,
    const int* __restrict__ ell, const int* __restrict__ cnt,
    float* __restrict__ xs, float* __restrict__ hsb,
    float* __restrict__ xc, float* __restrict__ xall) {
  cg::grid_group grid = cg::this_grid();
  __shared__ float As[32 * 132];
  __shared__ float Ws[128 * 128];
  __shared__ float xch[DIM];
  int tid = threadIdx.x;
  size_t rbase = (size_t)blockIdx.x * 32;
  if (blockIdx.x == 0 && tid < DIM) xc[tid] = 0.f;

  int j0 = (tid & 31) * 4;
  int r0 = (tid >> 5) * 4;
  int wv = tid >> 6, lane = tid & 63;

  for (int layer = 0; layer < 3; ++layer) {
    // stage W (64KB) and A-tile (own 32 rows of xs)
    for (int i = tid; i < 4096; i += 256)
      *(float4*)&Ws[i * 4] = *(const float4*)&WgT[(size_t)layer * DIM * DIM + i * 4];
    for (int i = tid; i < 1024; i += 256) {
      int r = i >> 5, c = i & 31;
      *(float4*)&As[r * 132 + c * 4] = *(const float4*)&xs[(rbase + r) * DIM + c * 4];
    }
    __syncthreads();
    // gemm: 4 rows x 4 cols per thread
    float acc[4][4];
    {
      float4 b4 = *(const float4*)&bg[layer * DIM + j0];
      float bv[4] = {b4.x, b4.y, b4.z, b4.w};
      #pragma unroll
      for (int ri = 0; ri < 4; ++ri)
        #pragma unroll
        for (int c = 0; c < 4; ++c) acc[ri][c] = bv[c];
    }
    for (int k4 = 0; k4 < 32; ++k4) {
      float a[4][4];
      #pragma unroll
      for (int ri = 0; ri < 4; ++ri)
        *(float4*)a[ri] = *(float4*)&As[(r0 + ri) * 132 + k4 * 4];
      #pragma unroll
      for (int kk = 0; kk < 4; ++kk) {
        float4 w4 = *(float4*)&Ws[(k4 * 4 + kk) * DIM + j0];
        float w[4] = {w4.x, w4.y, w4.z, w4.w};
        #pragma unroll
        for (int ri = 0; ri < 4; ++ri)
          #pragma unroll
          for (int c = 0; c < 4; ++c)
            acc[ri][c] += a[ri][kk] * w[c];
      }
    }
    #pragma unroll
    for (int ri = 0; ri < 4; ++ri) {
      float4 o;
      o.x = fmaxf(acc[ri][0], 0.f); o.y = fmaxf(acc[ri][1], 0.f);
      o.z = fmaxf(acc[ri][2], 0.f); o.w = fmaxf(acc[ri][3], 0.f);
      *(float4*)&hsb[(rbase + r0 + ri) * DIM + j0] = o;
    }
    grid.sync();   // all hs rows visible
    // spmv: 4 waves, 8 rows each; xs[row] += sum of neighbor hs rows
    for (int rr = 0; rr < 8; ++rr) {
      size_t row = rbase + wv * 8 + rr;
      int n = cnt[row];
      const int* er = ell + row * CAP;
      float2 a2 = *(float2*)&xs[row * DIM + lane * 2];
      int t2 = 0;
      for (; t2 + 1 < n; t2 += 2) {
        int ja = er[t2], jb = er[t2 + 1];
        float2 ha = *(const float2*)&hsb[(size_t)ja * DIM + lane * 2];
        float2 hb = *(const float2*)&hsb[(size_t)jb * DIM + lane * 2];
        a2.x += ha.x + hb.x; a2.y += ha.y + hb.y;
      }
      if (t2 < n) {
        int ja = er[t2];
        float2 ha = *(const float2*)&hsb[(size_t)ja * DIM + lane * 2];
        a2.x += ha.x; a2.y += ha.y;
      }
      *(float2*)&xs[row * DIM + lane * 2] = a2;
    }
    grid.sync();   // spmv reads done before next layer overwrites hsb
  }
  // column-sum of xs (own rows) -> atomic into xc
  {
    int c = tid & 127, h = tid >> 7;
    float s = 0.f;
    for (int r = h; r < 32; r += 2) s += xs[(rbase + r) * DIM + c];
    As[h * DIM + c] = s;
    __syncthreads();
    if (h == 0) atomicAdd(&xc[c], As[c] + As[DIM + c]);
  }
  grid.sync();
  // x-chain (3 iterations of relu(x@WaT+ba)) on block 0
  if (blockIdx.x == 0) {
    int j = tid;
    float bj = (j < DIM) ? ba[j] : 0.f;
    if (j < DIM) xch[j] = xc[j];
    __syncthreads();
    for (int i = 0; i < 3; ++i) {
      float a = bj;
      if (j < DIM) {
        for (int k = 0; k < DIM; ++k) a += xch[k] * WaT[k * DIM + j];
        a = fmaxf(a, 0.f);
      }
      __syncthreads();
      if (j < DIM) { xch[j] = a; xall[i * DIM + j] = a; }
      __syncthreads();
    }
  }
}

// ---------------- cooperative protein chain: 3x (conv23 -> gemm_relu -> attn) + colsum + final ----------------
__global__ __launch_bounds__(512) void k_prot(
    const float* __restrict__ cw, const float* __restrict__ cb,
    const float* __restrict__ WaT, const float* __restrict__ ba,
    const float* __restrict__ xall, const float* __restrict__ xc,
    const float* __restrict__ Wo, const float* __restrict__ bo,
    float* __restrict__ bufA, float* __restrict__ bufB,
    float* __restrict__ xp, float* __restrict__ out) {
  cg::grid_group grid = cg::this_grid();
  __shared__ float t[54][156];
  __shared__ float wl[23][24];
  __shared__ float Ws[128 * 128];
  __shared__ float As[32 * 132];
  __shared__ float hs2[32 * 132];
  __shared__ float xrow[DIM];
  __shared__ float r0s[8], r1s[8];
  int tid = threadIdx.x;
  size_t rbase = (size_t)blockIdx.x * 32;
  int l0 = blockIdx.x * 32;
  if (blockIdx.x == 0 && tid < DIM) xp[tid] = 0.f;
  // stage WaT once (constant across layers)
  for (int i = tid; i < 4096; i += 512)
    *(float4*)&Ws[i * 4] = *(const float4*)&WaT[i * 4];

  const float* cur = bufA;
  float* nxt = bufB;
  int lo = tid & 31, dg = tid >> 5;   // conv: 32 rows x 16 col-groups of 8
  int d0 = dg * 8;
  int j0 = (tid & 31) * 4, rg = tid >> 5;  // gemm: 2 rows x 4 cols per thread
  int wv = tid >> 6, lane = tid & 63;

  for (int layer = 0; layer < 3; ++layer) {
    __syncthreads();   // protect t/wl reuse across layers
    for (int i = tid; i < 529; i += 512) wl[i / 23][i % 23] = cw[layer * 529 + i];
    for (int i = tid; i < 54 * 156; i += 512) {
      int ll = i / 156, dd = i % 156;
      int gl = l0 - 11 + ll, gd = dd - 11;
      float v = 0.f;
      if (gl >= 0 && gl < LPROT && (unsigned)gd < DIM)
        v = cur[(size_t)gl * DIM + gd];
      t[ll][dd] = v;
    }
    __syncthreads();
    // conv: 8 outputs per thread (row lo, cols d0..d0+7)
    float acc[8];
    #pragma unroll
    for (int m = 0; m < 8; ++m) acc[m] = 0.f;
    for (int a = 0; a < 23; ++a) {
      float r[32];
      #pragma unroll
      for (int q = 0; q < 8; ++q)
        *(float4*)&r[4 * q] = *(float4*)&t[lo + a][d0 + 4 * q];
      float w[24];
      #pragma unroll
      for (int q = 0; q < 6; ++q)
        *(float4*)&w[4 * q] = *(float4*)&wl[a][4 * q];
      #pragma unroll
      for (int b = 0; b < 23; ++b)
        #pragma unroll
        for (int m = 0; m < 8; ++m)
          acc[m] += r[b + m] * w[b];
    }
    {
      float cbias = cb[layer];
      #pragma unroll
      for (int m = 0; m < 8; ++m)
        As[lo * 132 + d0 + m] = fmaxf(acc[m] + cbias, 0.f);
    }
    if (tid < DIM) xrow[tid] = xall[layer * DIM + tid];
    __syncthreads();
    // gemm: hs2 = relu(As @ WaT + ba); rows rg*2, rg*2+1
    float g[2][4];
    {
      float4 b4 = *(const float4*)&ba[j0];
      float bv[4] = {b4.x, b4.y, b4.z, b4.w};
      #pragma unroll
      for (int c = 0; c < 4; ++c) { g[0][c] = bv[c]; g[1][c] = bv[c]; }
    }
    for (int k4 = 0; k4 < 32; ++k4) {
      float a0[4], a1[4];
      *(float4*)a0 = *(float4*)&As[(rg * 2) * 132 + k4 * 4];
      *(float4*)a1 = *(float4*)&As[(rg * 2 + 1) * 132 + k4 * 4];
      #pragma unroll
      for (int kk = 0; kk < 4; ++kk) {
        float4 w4 = *(float4*)&Ws[(k4 * 4 + kk) * DIM + j0];
        float w[4] = {w4.x, w4.y, w4.z, w4.w};
        #pragma unroll
        for (int c = 0; c < 4; ++c) {
          g[0][c] += a0[kk] * w[c];
          g[1][c] += a1[kk] * w[c];
        }
      }
    }
    #pragma unroll
    for (int rr = 0; rr < 2; ++rr) {
      #pragma unroll
      for (int c = 0; c < 4; ++c)
        hs2[(rg * 2 + rr) * 132 + j0 + c] = fmaxf(g[rr][c], 0.f);
    }
    __syncthreads();
    // attn: weights = tanh(x . hs2_row); xsp_next = weights * hs2_row
    for (int rr = 0; rr < 4; ++rr) {
      int row = wv * 4 + rr;
      float2 h = *(float2*)&hs2[row * 132 + lane * 2];
      float p = h.x * xrow[lane * 2] + h.y * xrow[lane * 2 + 1];
      #pragma unroll
      for (int s = 32; s > 0; s >>= 1) p += __shfl_xor(p, s, 64);
      float wgt = tanhf(p);
      float2 o; o.x = wgt * h.x; o.y = wgt * h.y;
      *(float2*)&nxt[(rbase + row) * DIM + lane * 2] = o;
    }
    grid.sync();   // all xsp_next rows ready (conv halo for next layer)
    const float* tmp = cur; cur = nxt; nxt = (float*)tmp;
  }
  // column-sum of final xsp (own rows) -> atomic into xp
  {
    int c = tid & 127, h = tid >> 7;
    float s = 0.f;
    for (int r = h; r < 32; r += 4) s += cur[(rbase + r) * DIM + c];
    As[h * DIM + c] = s;
    __syncthreads();
    if (h == 0) atomicAdd(&xp[c], As[c] + As[DIM + c] + As[2 * DIM + c] + As[3 * DIM + c]);
  }
  grid.sync();
  // final softmax on block 0
  if (blockIdx.x == 0) {
    float p0 = 0.f, p1 = 0.f;
    if (tid < 256) {
      float y = (tid < DIM) ? xc[tid] : xp[tid - DIM];
      p0 = y * Wo[tid];
      p1 = y * Wo[256 + tid];
    }
    #pragma unroll
    for (int s = 32; s > 0; s >>= 1) {
      p0 += __shfl_xor(p0, s, 64);
      p1 += __shfl_xor(p1, s, 64);
    }
    if (lane == 0) { r0s[wv] = p0; r1s[wv] = p1; }
    __syncthreads();
    if (tid == 0) {
      float l0v = bo[0], l1v = bo[1];
      for (int w = 0; w < 8; ++w) { l0v += r0s[w]; l1v += r1s[w]; }
      float m = fmaxf(l0v, l1v);
      float e0 = expf(l0v - m), e1 = expf(l1v - m);
      float s = e0 + e1;
      out[0] = e0 / s;
      out[1] = e1 / s;
    }
  }
}

extern "C" void kernel_launch(void* const* d_in, const int* in_sizes, int n_in,
                              void* d_out, int out_size, void* d_ws, size_t ws_size,
                              hipStream_t stream) {
  const int*   fp     = (const int*)d_in[0];
  const int*   words  = (const int*)d_in[1];
  const float* adj    = (const float*)d_in[2];
  const float* emb_fp = (const float*)d_in[3];
  const float* emb_w  = (const float*)d_in[4];
  const float* Wg     = (const float*)d_in[5];
  const float* bg     = (const float*)d_in[6];
  const float* cw     = (const float*)d_in[7];
  const float* cb     = (const float*)d_in[8];
  const float* Wa     = (const float*)d_in[9];
  const float* ba     = (const float*)d_in[10];
  const float* Wo     = (const float*)d_in[11];
  const float* bo     = (const float*)d_in[12];
  float* out = (float*)d_out;

  float* ws   = (float*)d_ws;
  float* xs   = ws;                        // [8192,128]
  float* hsb  = ws + (size_t)NF;           // [8192,128] GNN hs staging
  float* bufA = ws + 2 * (size_t)NF;       // protein xsp ping
  float* bufB = ws + 3 * (size_t)NF;       // protein xsp pong
  int*   ell  = (int*)(ws + 4 * (size_t)NF);
  int*   cnt  = ell + (size_t)NATOMS * CAP;
  float* xc   = (float*)(cnt + NATOMS);    // [128]
  float* xp   = xc + DIM;                  // [128]
  float* xall = xp + DIM;                  // [3,128]
  float* WgT  = xall + 3 * DIM;            // [3,128,128]
  float* WaT  = WgT + 3 * DIM * DIM;       // [128,128]

  k_prep<<<dim3(2112), 256, 0, stream>>>(fp, words, emb_fp, emb_w, Wg, Wa,
                                         xs, bufA, WgT, WaT);
  k_build_ell<<<dim3(NATOMS / 4), 256, 0, stream>>>(adj, ell, cnt);

  {
    void* args[] = {(void*)&WgT, (void*)&bg, (void*)&WaT, (void*)&ba,
                    (void*)&ell, (void*)&cnt, (void*)&xs, (void*)&hsb,
                    (void*)&xc, (void*)&xall};
    hipLaunchCooperativeKernel((void*)k_gnn, dim3(256), dim3(256), args, 0, stream);
  }
  {
    void* args[] = {(void*)&cw, (void*)&cb, (void*)&WaT, (void*)&ba,
                    (void*)&xall, (void*)&xc, (void*)&Wo, (void*)&bo,
                    (void*)&bufA, (void*)&bufB, (void*)&xp, (void*)&out};
    hipLaunchCooperativeKernel((void*)k_prot, dim3(256), dim3(512), args, 0, stream);
  }
}

// Round 3
// 254.140 us; speedup vs baseline: 2.5444x; 2.5444x over previous
//
#include <hip/hip_runtime.h>
#include <math.h>

#define DIM 128
#define NATOMS 8192
#define LPROT 8192
#define CAP 64
#define NF (NATOMS*DIM)

// ---------------- prep: gathers + weight transposes + zero accumulators ----------------
__global__ __launch_bounds__(256) void k_prep(
    const int* __restrict__ fp, const int* __restrict__ words,
    const float* __restrict__ emb_fp, const float* __restrict__ emb_w,
    const float* __restrict__ Wg, const float* __restrict__ Wa,
    float* __restrict__ xs, float* __restrict__ xsp,
    float* __restrict__ WgT, float* __restrict__ WaT,
    float* __restrict__ xp) {
  int b = blockIdx.x, tid = threadIdx.x;
  if (b < 1024) {                      // gather atoms
    int i = b * 256 + tid;
    int row = i >> 5, c4 = i & 31;
    const float4* s = (const float4*)(emb_fp + (size_t)fp[row] * DIM);
    ((float4*)(xs + (size_t)row * DIM))[c4] = s[c4];
  } else if (b < 2048) {               // gather words
    int i = (b - 1024) * 256 + tid;
    int row = i >> 5, c4 = i & 31;
    const float4* s = (const float4*)(emb_w + (size_t)words[row] * DIM);
    ((float4*)(xsp + (size_t)row * DIM))[c4] = s[c4];
  } else if (b < 2112) {               // transpose Wg[0..2], Wa in 32x32 tiles
    __shared__ float tile[32][33];
    int sub = b - 2048;
    int m = sub >> 4, t = sub & 15;
    int tx = t & 3, ty = t >> 2;
    const float* src = (m < 3) ? Wg + m * DIM * DIM : Wa;
    float*       dst = (m < 3) ? WgT + m * DIM * DIM : WaT;
    int x = tid & 31, y0 = tid >> 5;
    int xg = tx * 32 + x;
    for (int i = y0; i < 32; i += 8)
      tile[i][x] = src[(ty * 32 + i) * DIM + xg];
    __syncthreads();
    int xo = ty * 32 + x;
    for (int i = y0; i < 32; i += 8)
      dst[(tx * 32 + i) * DIM + xo] = tile[x][i];
  } else {                             // zero atomic accumulator
    if (tid < DIM) xp[tid] = 0.f;
  }
}

// ---------------- build ELL from dense binary adjacency (HBM-floor ~41us) ----------------
__global__ void k_build_ell(const float* __restrict__ adj, int* __restrict__ ell,
                            int* __restrict__ cnt) {
  int wv = threadIdx.x >> 6, lane = threadIdx.x & 63;
  int row = blockIdx.x * 4 + wv;
  const float4* rp = (const float4*)(adj + (size_t)row * NATOMS);
  int* er = ell + (size_t)row * CAP;
  int c = 0;
  for (int it = 0; it < NATOMS / 256; ++it) {
    float4 v = rp[(size_t)it * 64 + lane];
    float f[4] = {v.x, v.y, v.z, v.w};
    #pragma unroll
    for (int j = 0; j < 4; ++j) {
      bool nz = (f[j] != 0.0f);
      unsigned long long m = __ballot(nz);
      if (nz) {
        int pos = c + __popcll(m & ((1ull << lane) - 1ull));
        if (pos < CAP) er[pos] = it * 256 + lane * 4 + j;
      }
      c += __popcll(m);
    }
  }
  if (lane == 0) cnt[row] = c > CAP ? CAP : c;
}

// ---------------- GNN gemm: C = relu(A @ W^T + b), 32 rows/block, 256 blocks ----------------
__global__ __launch_bounds__(256) void k_gemm_g(
    const float* __restrict__ A, const float* __restrict__ WT,
    const float* __restrict__ bias, float* __restrict__ C) {
  __shared__ float As[32 * 132];
  __shared__ float Ws[128 * 128];
  int tid = threadIdx.x;
  size_t rbase = (size_t)blockIdx.x * 32;
  int j0 = (tid & 31) * 4, r0 = (tid >> 5) * 4;
  for (int i = tid; i < 4096; i += 256)
    ((float4*)Ws)[i] = ((const float4*)WT)[i];
  for (int i = tid; i < 1024; i += 256) {
    int r = i >> 5, c = i & 31;
    *(float4*)&As[r * 132 + c * 4] = *(const float4*)&A[(rbase + r) * DIM + c * 4];
  }
  __syncthreads();
  float acc[4][4];
  {
    float4 b4 = *(const float4*)&bias[j0];
    float bv[4] = {b4.x, b4.y, b4.z, b4.w};
    #pragma unroll
    for (int ri = 0; ri < 4; ++ri)
      #pragma unroll
      for (int c = 0; c < 4; ++c) acc[ri][c] = bv[c];
  }
  for (int k4 = 0; k4 < 32; ++k4) {
    float a[4][4];
    #pragma unroll
    for (int ri = 0; ri < 4; ++ri)
      *(float4*)a[ri] = *(float4*)&As[(r0 + ri) * 132 + k4 * 4];
    #pragma unroll
    for (int kk = 0; kk < 4; ++kk) {
      float4 w4 = *(float4*)&Ws[(k4 * 4 + kk) * DIM + j0];
      float w[4] = {w4.x, w4.y, w4.z, w4.w};
      #pragma unroll
      for (int ri = 0; ri < 4; ++ri)
        #pragma unroll
        for (int c = 0; c < 4; ++c)
          acc[ri][c] += a[ri][kk] * w[c];
    }
  }
  #pragma unroll
  for (int ri = 0; ri < 4; ++ri) {
    float4 o;
    o.x = fmaxf(acc[ri][0], 0.f); o.y = fmaxf(acc[ri][1], 0.f);
    o.z = fmaxf(acc[ri][2], 0.f); o.w = fmaxf(acc[ri][3], 0.f);
    *(float4*)&C[(rbase + r0 + ri) * DIM + j0] = o;
  }
}

// ---------------- spmv: xs[row] += sum_{j in nbr(row)} hs[j]; wave per row ----------------
__global__ void k_spmv_add(const int* __restrict__ ell, const int* __restrict__ cnt,
                           const float* __restrict__ hs, float* __restrict__ xs) {
  int wv = threadIdx.x >> 6, lane = threadIdx.x & 63;
  int row = blockIdx.x * 4 + wv;
  int n = cnt[row];
  const int* er = ell + (size_t)row * CAP;
  float2 acc = *(const float2*)&xs[(size_t)row * DIM + lane * 2];
  int t = 0;
  for (; t + 4 <= n; t += 4) {
    int ja = er[t], jb = er[t + 1], jc = er[t + 2], jd = er[t + 3];
    float2 ha = *(const float2*)&hs[(size_t)ja * DIM + lane * 2];
    float2 hb = *(const float2*)&hs[(size_t)jb * DIM + lane * 2];
    float2 hc = *(const float2*)&hs[(size_t)jc * DIM + lane * 2];
    float2 hd = *(const float2*)&hs[(size_t)jd * DIM + lane * 2];
    acc.x += (ha.x + hb.x) + (hc.x + hd.x);
    acc.y += (ha.y + hb.y) + (hc.y + hd.y);
  }
  for (; t < n; ++t) {
    int j = er[t];
    float2 h = *(const float2*)&hs[(size_t)j * DIM + lane * 2];
    acc.x += h.x; acc.y += h.y;
  }
  *(float2*)&xs[(size_t)row * DIM + lane * 2] = acc;
}

// ---------------- two-stage column sum ----------------
__global__ void k_colsum_part(const float* __restrict__ in, float* __restrict__ part) {
  int c = threadIdx.x & 127, h = threadIdx.x >> 7;
  size_t r0 = (size_t)blockIdx.x * 128;
  float s = 0.f;
  for (int t = 0; t < 64; ++t) s += in[(r0 + h + 2 * t) * DIM + c];
  __shared__ float buf[DIM];
  if (h) buf[c] = s;
  __syncthreads();
  if (!h) part[blockIdx.x * DIM + c] = s + buf[c];
}

__global__ void k_colsum_final(const float* __restrict__ part, float* __restrict__ o) {
  int c = threadIdx.x;
  float s = 0.f;
  for (int b = 0; b < 64; ++b) s += part[b * DIM + c];
  o[c] = s;
}

// ---------------- x-chain: 3 iterations of relu(x@WaT+ba) ----------------
__global__ void k_xchain(const float* __restrict__ xc, const float* __restrict__ WaT,
                         const float* __restrict__ ba, float* __restrict__ xall) {
  __shared__ float xb[DIM];
  int j = threadIdx.x;
  xb[j] = xc[j];
  float bj = ba[j];
  for (int i = 0; i < 3; ++i) {
    __syncthreads();
    float acc = bj;
    for (int k = 0; k < DIM; ++k) acc += xb[k] * WaT[k * DIM + j];
    acc = fmaxf(acc, 0.f);
    __syncthreads();
    xb[j] = acc;
    xall[i * DIM + j] = acc;
  }
}

// ---------------- fused protein layer: conv23 -> gemm_relu -> attn (-> colsum) ----------------
__global__ __launch_bounds__(512) void k_prot_layer(
    const float* __restrict__ cur, float* __restrict__ nxt,
    const float* __restrict__ cw, const float* __restrict__ cb,
    const float* __restrict__ WaT, const float* __restrict__ ba,
    const float* __restrict__ xrow_g, float* __restrict__ xp, int last) {
  __shared__ float U[128 * 128];          // union: conv tile t[54][156] (8424 f) / Ws (16384 f)
  __shared__ float wl[23 * 24];
  __shared__ float As[32 * 132];
  __shared__ float hs2[32 * 132];
  __shared__ float xrow[DIM];
  int tid = threadIdx.x;
  size_t rbase = (size_t)blockIdx.x * 32;
  int l0 = blockIdx.x * 32;

  // stage conv weights + input tile (rows l0-11 .. l0+42, cols -11..138 zero-padded)
  for (int i = tid; i < 529; i += 512) wl[i] = cw[i];
  for (int i = tid; i < 54 * 156; i += 512) {
    int ll = i / 156, dd = i % 156;
    int gl = l0 - 11 + ll, gd = dd - 11;
    float v = 0.f;
    if (gl >= 0 && gl < LPROT && (unsigned)gd < DIM)
      v = cur[(size_t)gl * DIM + gd];
    U[ll * 156 + dd] = v;
  }
  if (tid < DIM) xrow[tid] = xrow_g[tid];
  __syncthreads();

  // conv: thread -> row (tid&31), 8 cols at d0=(tid>>5)*8
  {
    int lo = tid & 31, d0 = (tid >> 5) * 8;
    float acc[8];
    #pragma unroll
    for (int m = 0; m < 8; ++m) acc[m] = 0.f;
    for (int a = 0; a < 23; ++a) {
      float r[32];
      #pragma unroll
      for (int q = 0; q < 8; ++q)
        *(float4*)&r[4 * q] = *(float4*)&U[(lo + a) * 156 + d0 + 4 * q];
      float w[24];
      #pragma unroll
      for (int q = 0; q < 6; ++q)
        *(float4*)&w[4 * q] = *(float4*)&wl[a * 23 + 4 * q - (a ? a : 0) * 0 + 0];
      // note: wl is [23][23] flat; fix index below
      #pragma unroll
      for (int q = 0; q < 6; ++q)
        *(float4*)&w[4 * q] = *(float4*)&wl[0];  // placeholder overwritten below
      #pragma unroll
      for (int b = 0; b < 23; ++b) w[b] = wl[a * 23 + b];
      #pragma unroll
      for (int b = 0; b < 23; ++b)
        #pragma unroll
        for (int m = 0; m < 8; ++m)
          acc[m] += r[b + m] * w[b];
    }
    float cbias = cb[0];
    #pragma unroll
    for (int m = 0; m < 8; ++m)
      As[lo * 132 + d0 + m] = fmaxf(acc[m] + cbias, 0.f);
  }
  __syncthreads();   // conv reads of U done; As ready

  // stage WaT into U
  for (int i = tid; i < 4096; i += 512)
    ((float4*)U)[i] = ((const float4*)WaT)[i];
  __syncthreads();

  // gemm: hs2 = relu(As @ WaT + ba); thread -> 2 rows x 4 cols
  {
    int j0 = (tid & 31) * 4, rg = tid >> 5;
    float g[2][4];
    float4 b4 = *(const float4*)&ba[j0];
    float bv[4] = {b4.x, b4.y, b4.z, b4.w};
    #pragma unroll
    for (int c = 0; c < 4; ++c) { g[0][c] = bv[c]; g[1][c] = bv[c]; }
    for (int k4 = 0; k4 < 32; ++k4) {
      float a0[4], a1[4];
      *(float4*)a0 = *(float4*)&As[(rg * 2) * 132 + k4 * 4];
      *(float4*)a1 = *(float4*)&As[(rg * 2 + 1) * 132 + k4 * 4];
      #pragma unroll
      for (int kk = 0; kk < 4; ++kk) {
        float4 w4 = *(float4*)&U[(k4 * 4 + kk) * DIM + j0];
        float w[4] = {w4.x, w4.y, w4.z, w4.w};
        #pragma unroll
        for (int c = 0; c < 4; ++c) {
          g[0][c] += a0[kk] * w[c];
          g[1][c] += a1[kk] * w[c];
        }
      }
    }
    #pragma unroll
    for (int rr = 0; rr < 2; ++rr)
      #pragma unroll
      for (int c = 0; c < 4; ++c)
        hs2[(rg * 2 + rr) * 132 + j0 + c] = fmaxf(g[rr][c], 0.f);
  }
  __syncthreads();

  // attn: 8 waves x 4 rows; weights = tanh(x . hs2_row); out = weights * hs2_row
  int wv = tid >> 6, lane = tid & 63;
  float cx = 0.f, cy = 0.f;
  float x0 = xrow[lane * 2], x1 = xrow[lane * 2 + 1];
  for (int rr = 0; rr < 4; ++rr) {
    int row = wv * 4 + rr;
    float2 h = *(float2*)&hs2[row * 132 + lane * 2];
    float p = h.x * x0 + h.y * x1;
    #pragma unroll
    for (int s = 32; s > 0; s >>= 1) p += __shfl_xor(p, s, 64);
    float wgt = tanhf(p);
    float ox = wgt * h.x, oy = wgt * h.y;
    if (!last) {
      float2 o; o.x = ox; o.y = oy;
      *(float2*)&nxt[(rbase + row) * DIM + lane * 2] = o;
    } else {
      cx += ox; cy += oy;
    }
  }
  if (last) {   // fused column-sum -> atomicAdd into xp
    As[wv * DIM + lane * 2] = cx;
    As[wv * DIM + lane * 2 + 1] = cy;
    __syncthreads();
    if (wv == 0) {
      float sx = 0.f, sy = 0.f;
      #pragma unroll
      for (int w = 0; w < 8; ++w) {
        sx += As[w * DIM + lane * 2];
        sy += As[w * DIM + lane * 2 + 1];
      }
      atomicAdd(&xp[lane * 2], sx);
      atomicAdd(&xp[lane * 2 + 1], sy);
    }
  }
}

// ---------------- final: softmax([xc|xp] @ Wo^T + bo) ----------------
__global__ void k_final(const float* __restrict__ xc, const float* __restrict__ xp,
                        const float* __restrict__ Wo, const float* __restrict__ bo,
                        float* __restrict__ out) {
  int t = threadIdx.x;
  float y = (t < DIM) ? xc[t] : xp[t - DIM];
  float p0 = y * Wo[t];
  float p1 = y * Wo[256 + t];
  #pragma unroll
  for (int s = 32; s > 0; s >>= 1) {
    p0 += __shfl_xor(p0, s, 64);
    p1 += __shfl_xor(p1, s, 64);
  }
  __shared__ float r0[4], r1[4];
  int wv = t >> 6;
  if ((t & 63) == 0) { r0[wv] = p0; r1[wv] = p1; }
  __syncthreads();
  if (t == 0) {
    float l0 = r0[0] + r0[1] + r0[2] + r0[3] + bo[0];
    float l1 = r1[0] + r1[1] + r1[2] + r1[3] + bo[1];
    float m = fmaxf(l0, l1);
    float e0 = expf(l0 - m), e1 = expf(l1 - m);
    float s = e0 + e1;
    out[0] = e0 / s;
    out[1] = e1 / s;
  }
}

extern "C" void kernel_launch(void* const* d_in, const int* in_sizes, int n_in,
                              void* d_out, int out_size, void* d_ws, size_t ws_size,
                              hipStream_t stream) {
  const int*   fp     = (const int*)d_in[0];
  const int*   words  = (const int*)d_in[1];
  const float* adj    = (const float*)d_in[2];
  const float* emb_fp = (const float*)d_in[3];
  const float* emb_w  = (const float*)d_in[4];
  const float* Wg     = (const float*)d_in[5];
  const float* bg     = (const float*)d_in[6];
  const float* cw     = (const float*)d_in[7];
  const float* cb     = (const float*)d_in[8];
  const float* Wa     = (const float*)d_in[9];
  const float* ba     = (const float*)d_in[10];
  const float* Wo     = (const float*)d_in[11];
  const float* bo     = (const float*)d_in[12];
  float* out = (float*)d_out;

  float* ws   = (float*)d_ws;
  float* xs   = ws;                        // [8192,128]
  float* hsb  = ws + (size_t)NF;           // [8192,128] GNN hs staging
  float* bufA = ws + 2 * (size_t)NF;       // protein xsp ping
  float* bufB = ws + 3 * (size_t)NF;       // protein xsp pong
  int*   ell  = (int*)(ws + 4 * (size_t)NF);
  int*   cnt  = ell + (size_t)NATOMS * CAP;
  float* part = (float*)(cnt + NATOMS);    // [64,128]
  float* xc   = part + 64 * DIM;           // [128]
  float* xp   = xc + DIM;                  // [128]
  float* xall = xp + DIM;                  // [3,128]
  float* WgT  = xall + 3 * DIM;            // [3,128,128]
  float* WaT  = WgT + 3 * DIM * DIM;       // [128,128]

  k_prep<<<dim3(2113), 256, 0, stream>>>(fp, words, emb_fp, emb_w, Wg, Wa,
                                         xs, bufA, WgT, WaT, xp);
  k_build_ell<<<dim3(NATOMS / 4), 256, 0, stream>>>(adj, ell, cnt);

  for (int i = 0; i < 3; ++i) {
    k_gemm_g<<<dim3(NATOMS / 32), 256, 0, stream>>>(xs, WgT + i * DIM * DIM, bg + i * DIM, hsb);
    k_spmv_add<<<dim3(NATOMS / 4), 256, 0, stream>>>(ell, cnt, hsb, xs);
  }
  k_colsum_part<<<dim3(64), 256, 0, stream>>>(xs, part);
  k_colsum_final<<<dim3(1), DIM, 0, stream>>>(part, xc);
  k_xchain<<<dim3(1), DIM, 0, stream>>>(xc, WaT, ba, xall);

  const float* cur = bufA;
  float* nxt = bufB;
  for (int i = 0; i < 3; ++i) {
    k_prot_layer<<<dim3(LPROT / 32), 512, 0, stream>>>(
        cur, nxt, cw + i * 529, cb + i, WaT, ba, xall + i * DIM, xp, (i == 2) ? 1 : 0);
    const float* tmp = cur; cur = nxt; nxt = (float*)tmp;
  }
  k_final<<<dim3(1), 256, 0, stream>>>(xc, xp, Wo, bo, out);
}